// Round 1
// baseline (150.236 us; speedup 1.0000x reference)
//
#include <hip/hip_runtime.h>

// Causal linear attention (ELU+1 feature map), chunked formulation.
// B=2, L=4096, dk=dv=128, fp32. Chunk C=128 -> NC=32 chunks/batch.
//
//  k_chunk_kv : S_c = phi(K_c)^T V_c  (128x128), ksum_c = sum phi(K_c)  per (b,c)
//  k_scan     : in-place EXCLUSIVE prefix over chunk axis for S and ksum
//  k_out      : A = causal_mask(phi(Q) phi(K)^T); out = A V + phi(Q) S_prev;
//               z = rowsum(A) + phi(Q).kprev; out /= (z+eps)

#define EPS 1e-6f

constexpr int Bc = 2;
constexpr int L  = 4096;
constexpr int D  = 128;   // dk == dv
constexpr int C  = 128;   // chunk length
constexpr int NC = L / C; // 32

__device__ __forceinline__ float phi(float x) {
    // elu(x)+1 == x+1 (x>0), exp(x) (x<=0)
    return x > 0.0f ? x + 1.0f : __expf(x);
}

// ---------------------------------------------------------------------------
// Kernel 1: per-chunk KV outer-product sums.  grid (NC, B), 256 threads.
// Each thread computes an 8x8 register tile of the 128x128 S_c output.
// i rows = ty*8+u (contiguous 8), j cols = {tx*4+v, 64+tx*4+v} (split groups
// so LDS reads are <=2-way bank aliased and global stores are float4).
// ---------------------------------------------------------------------------
__global__ __launch_bounds__(256) void k_chunk_kv(
    const float* __restrict__ K, const float* __restrict__ V,
    float* __restrict__ S, float* __restrict__ Ksum) {
    const int c = blockIdx.x, b = blockIdx.y;
    const int tid = threadIdx.x;
    const int tx = tid & 15, ty = tid >> 4;
    __shared__ float sK[32 * 128];
    __shared__ float sV[32 * 128];
    const size_t base = ((size_t)b * L + (size_t)c * C) * D;

    float acc[8][8];
#pragma unroll
    for (int u = 0; u < 8; ++u)
#pragma unroll
        for (int v = 0; v < 8; ++v) acc[u][v] = 0.0f;
    float kacc[8];
#pragma unroll
    for (int u = 0; u < 8; ++u) kacc[u] = 0.0f;

    for (int lt = 0; lt < C / 32; ++lt) {
        // stage 32x128 tiles (coalesced float4 loads)
#pragma unroll
        for (int k = 0; k < 4; ++k) {
            int fi  = tid + 256 * k;  // float4 index 0..1023
            int row = fi >> 5;        // 32 float4 per row
            int c4  = fi & 31;
            const float4 k4 = *(const float4*)(K + base + (size_t)(lt * 32 + row) * D + c4 * 4);
            const float4 v4 = *(const float4*)(V + base + (size_t)(lt * 32 + row) * D + c4 * 4);
            float4 pk;
            pk.x = phi(k4.x); pk.y = phi(k4.y); pk.z = phi(k4.z); pk.w = phi(k4.w);
            *(float4*)(sK + row * 128 + c4 * 4) = pk;
            *(float4*)(sV + row * 128 + c4 * 4) = v4;
        }
        __syncthreads();
#pragma unroll 4
        for (int l = 0; l < 32; ++l) {
            float kv[8], vv[8];
#pragma unroll
            for (int u = 0; u < 8; ++u) kv[u] = sK[l * 128 + ty * 8 + u];
#pragma unroll
            for (int v4 = 0; v4 < 4; ++v4) {
                vv[v4]     = sV[l * 128 + tx * 4 + v4];
                vv[4 + v4] = sV[l * 128 + 64 + tx * 4 + v4];
            }
#pragma unroll
            for (int u = 0; u < 8; ++u)
#pragma unroll
                for (int v = 0; v < 8; ++v) acc[u][v] += kv[u] * vv[v];
            if (tx == 0) {
#pragma unroll
                for (int u = 0; u < 8; ++u) kacc[u] += kv[u];
            }
        }
        __syncthreads();
    }

    float* Sout = S + ((size_t)(b * NC + c)) * D * D;
#pragma unroll
    for (int u = 0; u < 8; ++u) {
        int i = ty * 8 + u;
        float4 o0 = make_float4(acc[u][0], acc[u][1], acc[u][2], acc[u][3]);
        float4 o1 = make_float4(acc[u][4], acc[u][5], acc[u][6], acc[u][7]);
        *(float4*)(Sout + i * 128 + tx * 4)      = o0;
        *(float4*)(Sout + i * 128 + 64 + tx * 4) = o1;
    }
    if (tx == 0) {
#pragma unroll
        for (int u = 0; u < 8; ++u)
            Ksum[((size_t)(b * NC + c)) * D + ty * 8 + u] = kacc[u];
    }
}

// ---------------------------------------------------------------------------
// Kernel 2: exclusive prefix over chunk axis, in place. One thread per
// (b, element); 32 sequential load/stores, coalesced across threads.
// ---------------------------------------------------------------------------
__global__ __launch_bounds__(256) void k_scan(float* __restrict__ S,
                                              float* __restrict__ Ksum) {
    const int SD = D * D;  // 16384
    int idx = blockIdx.x * 256 + threadIdx.x;
    if (idx < Bc * SD) {
        int b = idx / SD, e = idx % SD;
        float run = 0.0f;
        for (int c = 0; c < NC; ++c) {
            size_t off = ((size_t)(b * NC + c)) * SD + e;
            float t = S[off];
            S[off]  = run;
            run += t;
        }
    } else if (idx < Bc * SD + Bc * D) {
        int r = idx - Bc * SD;
        int b = r >> 7, i = r & 127;
        float run = 0.0f;
        for (int c = 0; c < NC; ++c) {
            size_t off = ((size_t)(b * NC + c)) * D + i;
            float t = Ksum[off];
            Ksum[off] = run;
            run += t;
        }
    }
}

// ---------------------------------------------------------------------------
// Kernel 3: per-chunk output.  grid (NC, B), 256 threads.
// LDS: sA 128x129 fp32 (pad-129 -> column reads conflict-free), sQ/sKt
// 128x34 (pad-34 -> 2-way max, free), sB2 32x128 staging, ~115.5 KB total
// (gfx950 LDS is 160 KiB/CU; 1 block/CU).
// ---------------------------------------------------------------------------
__global__ __launch_bounds__(256) void k_out(
    const float* __restrict__ Q, const float* __restrict__ K,
    const float* __restrict__ V, const float* __restrict__ S,
    const float* __restrict__ Ksum, float* __restrict__ Out) {
    const int c = blockIdx.x, b = blockIdx.y;
    const int tid = threadIdx.x;
    const int tx = tid & 15, ty = tid >> 4;
    __shared__ float sA[128 * 129];
    __shared__ float sQ[128 * 34];
    __shared__ float sKt[128 * 34];
    __shared__ float sB2[32 * 128];
    __shared__ float sKp[128];
    __shared__ float zs[128];
    const size_t base  = ((size_t)b * L + (size_t)c * C) * D;
    const size_t sbase = ((size_t)(b * NC + c)) * (size_t)D * D;

    if (tid < 128) sKp[tid] = Ksum[((size_t)(b * NC + c)) * D + tid];

    float aacc[8][8];
#pragma unroll
    for (int u = 0; u < 8; ++u)
#pragma unroll
        for (int v = 0; v < 8; ++v) aacc[u][v] = 0.0f;
    float zacc = 0.0f;  // inter-chunk z partial (valid for tid<128)

    // ---- Phase B: A = phi(Q) phi(K)^T, reduce over i in 4 tiles of 32 ----
    for (int it = 0; it < 4; ++it) {
#pragma unroll
        for (int k = 0; k < 4; ++k) {
            int fi  = tid + 256 * k;  // 0..1023 float4s of a 128x32 tile
            int row = fi >> 3;        // 8 float4 per row
            int c4  = fi & 7;
            float4 q4 = *(const float4*)(Q + base + (size_t)row * D + it * 32 + c4 * 4);
            float4 k4 = *(const float4*)(K + base + (size_t)row * D + it * 32 + c4 * 4);
            float* dq = sQ + row * 34 + c4 * 4;
            dq[0] = phi(q4.x); dq[1] = phi(q4.y); dq[2] = phi(q4.z); dq[3] = phi(q4.w);
            float* dk = sKt + row * 34 + c4 * 4;
            dk[0] = phi(k4.x); dk[1] = phi(k4.y); dk[2] = phi(k4.z); dk[3] = phi(k4.w);
        }
        __syncthreads();
#pragma unroll 4
        for (int ii = 0; ii < 32; ++ii) {
            float qv[8], kv[8];
#pragma unroll
            for (int u = 0; u < 8; ++u) qv[u] = sQ[(ty * 8 + u) * 34 + ii];
#pragma unroll
            for (int v4 = 0; v4 < 4; ++v4) {
                kv[v4]     = sKt[(tx * 4 + v4) * 34 + ii];
                kv[4 + v4] = sKt[(64 + tx * 4 + v4) * 34 + ii];
            }
#pragma unroll
            for (int u = 0; u < 8; ++u)
#pragma unroll
                for (int v = 0; v < 8; ++v) aacc[u][v] += qv[u] * kv[v];
        }
        if (tid < 128) {  // inter-chunk z: phiQ[l][i] * kprev[i], same i-tiling
#pragma unroll 8
            for (int ii = 0; ii < 32; ++ii)
                zacc += sQ[tid * 34 + ii] * sKp[it * 32 + ii];
        }
        __syncthreads();
    }

    // ---- causal mask + store A to LDS ----
#pragma unroll
    for (int u = 0; u < 8; ++u) {
        int l = ty * 8 + u;
#pragma unroll
        for (int v4 = 0; v4 < 4; ++v4) {
            int j0 = tx * 4 + v4;
            int j1 = 64 + tx * 4 + v4;
            sA[l * 129 + j0] = (j0 <= l) ? aacc[u][v4] : 0.0f;
            sA[l * 129 + j1] = (j1 <= l) ? aacc[u][4 + v4] : 0.0f;
        }
    }
    __syncthreads();
    if (tid < 128) {  // z = inter + intra (rowsum of masked A) + eps
        float zi = 0.0f;
#pragma unroll 8
        for (int j = 0; j < 128; ++j) zi += sA[tid * 129 + j];
        zs[tid] = zacc + zi + EPS;
    }

    float acc[8][8];
#pragma unroll
    for (int u = 0; u < 8; ++u)
#pragma unroll
        for (int v = 0; v < 8; ++v) acc[u][v] = 0.0f;

    // ---- Phase B2: acc += masked A @ V, reduce over l' in 4 tiles of 32 ----
    for (int lt = 0; lt < 4; ++lt) {
#pragma unroll
        for (int k = 0; k < 4; ++k) {
            int fi  = tid + 256 * k;
            int row = fi >> 5;
            int c4  = fi & 31;
            *(float4*)(sB2 + row * 128 + c4 * 4) =
                *(const float4*)(V + base + (size_t)(lt * 32 + row) * D + c4 * 4);
        }
        __syncthreads();  // also publishes zs
#pragma unroll 4
        for (int ii = 0; ii < 32; ++ii) {
            float av[8], vv[8];
#pragma unroll
            for (int u = 0; u < 8; ++u) av[u] = sA[(ty * 8 + u) * 129 + lt * 32 + ii];
#pragma unroll
            for (int v4 = 0; v4 < 4; ++v4) {
                vv[v4]     = sB2[ii * 128 + tx * 4 + v4];
                vv[4 + v4] = sB2[ii * 128 + 64 + tx * 4 + v4];
            }
#pragma unroll
            for (int u = 0; u < 8; ++u)
#pragma unroll
                for (int v = 0; v < 8; ++v) acc[u][v] += av[u] * vv[v];
        }
        __syncthreads();
    }

    // ---- Phase A: acc += phi(Q) @ S_prev, reduce over i in 4 tiles of 32 ----
    for (int it = 0; it < 4; ++it) {
#pragma unroll
        for (int k = 0; k < 4; ++k) {
            int fi  = tid + 256 * k;
            int row = fi >> 3;
            int c4  = fi & 7;
            float4 q4 = *(const float4*)(Q + base + (size_t)row * D + it * 32 + c4 * 4);
            float* dq = sQ + row * 34 + c4 * 4;
            dq[0] = phi(q4.x); dq[1] = phi(q4.y); dq[2] = phi(q4.z); dq[3] = phi(q4.w);
        }
#pragma unroll
        for (int k = 0; k < 4; ++k) {
            int fi  = tid + 256 * k;
            int row = fi >> 5;
            int c4  = fi & 31;
            *(float4*)(sB2 + row * 128 + c4 * 4) =
                *(const float4*)(S + sbase + (size_t)(it * 32 + row) * D + c4 * 4);
        }
        __syncthreads();
#pragma unroll 4
        for (int ii = 0; ii < 32; ++ii) {
            float qv[8], sv[8];
#pragma unroll
            for (int u = 0; u < 8; ++u) qv[u] = sQ[(ty * 8 + u) * 34 + ii];
#pragma unroll
            for (int v4 = 0; v4 < 4; ++v4) {
                sv[v4]     = sB2[ii * 128 + tx * 4 + v4];
                sv[4 + v4] = sB2[ii * 128 + 64 + tx * 4 + v4];
            }
#pragma unroll
            for (int u = 0; u < 8; ++u)
#pragma unroll
                for (int v = 0; v < 8; ++v) acc[u][v] += qv[u] * sv[v];
        }
        __syncthreads();
    }

    // ---- normalize + store ----
#pragma unroll
    for (int u = 0; u < 8; ++u) {
        int l = ty * 8 + u;
        float rz = 1.0f / zs[l];
        float4 o0 = make_float4(acc[u][0] * rz, acc[u][1] * rz, acc[u][2] * rz, acc[u][3] * rz);
        float4 o1 = make_float4(acc[u][4] * rz, acc[u][5] * rz, acc[u][6] * rz, acc[u][7] * rz);
        *(float4*)(Out + base + (size_t)l * D + tx * 4)      = o0;
        *(float4*)(Out + base + (size_t)l * D + 64 + tx * 4) = o1;
    }
}

extern "C" void kernel_launch(void* const* d_in, const int* in_sizes, int n_in,
                              void* d_out, int out_size, void* d_ws, size_t ws_size,
                              hipStream_t stream) {
    const float* Q = (const float*)d_in[0];
    const float* K = (const float*)d_in[1];
    const float* V = (const float*)d_in[2];
    float* Out  = (float*)d_out;
    float* S    = (float*)d_ws;                       // B*NC*D*D = 4 MB
    float* Ksum = S + (size_t)Bc * NC * D * D;        // B*NC*D   = 32 KB

    k_chunk_kv<<<dim3(NC, Bc), 256, 0, stream>>>(K, V, S, Ksum);
    int total = Bc * D * D + Bc * D;
    k_scan<<<dim3((total + 255) / 256), 256, 0, stream>>>(S, Ksum);
    k_out<<<dim3(NC, Bc), 256, 0, stream>>>(Q, K, V, S, Ksum, Out);
}

// Round 3
// 84.134 us; speedup vs baseline: 1.7857x; 1.7857x over previous
//
#include <hip/hip_runtime.h>

// Causal linear attention (ELU+1), chunked, bf16-MFMA version.
// B=2, L=4096, dk=dv=128 fp32 in/out. Chunk C=128, NC=32.
//
//  k1     (NC,B,2):  ST_c[v][i] = sum_l V[l][v] phiK[l][i]  (bf16 MFMA,
//                    v split 2x64), chunk ksum. SB bf16 chunk sums.
//  k_scan          :  exclusive prefix over chunks: SB (bf16, fp32 run),
//                    Ksum (fp32, in place).
//  k_out  (NC,B,4):  rows split 4x32.  A=phiQ phiK^T (MFMA, natural NT
//                    layout), causal mask -> Am bf16 LDS; out = Am V +
//                    phiQ S_prev (MFMA); z = rowsum(Am) + phiQ.kprev.
//
// R2 bug: S_prev restage used v=fi>>3,ch=fi&7 (64-elem rows) instead of
// v=fi>>4,ch=fi&15 (128 bf16 = 16 uint4/row) -> wrote 34KB past sB,
// corrupting sAm/sKp/sZ -> inf. Fixed here; layouts re-audited.

#define EPS 1e-6f

constexpr int Bc = 2;
constexpr int L  = 4096;
constexpr int D  = 128;
constexpr int C  = 128;
constexpr int NC = L / C;   // 32
constexpr int P  = 136;     // LDS row pitch in bf16 units (rows 16B-aligned)

typedef short sh8 __attribute__((ext_vector_type(8)));   // 8 bf16 (4 VGPR)
typedef float f4  __attribute__((ext_vector_type(4)));   // MFMA C/D

__device__ __forceinline__ float phi(float x) {
    return x > 0.0f ? x + 1.0f : __expf(x);
}
__device__ __forceinline__ unsigned short f2bf(float f) {
    unsigned u = __float_as_uint(f);
    unsigned r = (u + 0x7FFFu + ((u >> 16) & 1u)) >> 16;   // RNE
    return (unsigned short)r;
}
__device__ __forceinline__ float bf2f(unsigned short h) {
    return __uint_as_float(((unsigned)h) << 16);
}

// ---------------------------------------------------------------------------
// k1: per-chunk ST[v][i] = sum_l V[l][v] phiK[l][i], bf16 out, + chunk ksum.
// grid (NC, B, 2): z splits v into 2x64.  256 threads = 4 waves.
// ---------------------------------------------------------------------------
__global__ __launch_bounds__(256) void k1(
    const float* __restrict__ K, const float* __restrict__ V,
    unsigned short* __restrict__ SB, float* __restrict__ Ksum) {
    const int c = blockIdx.x, b = blockIdx.y, vs = blockIdx.z;
    const int tid = threadIdx.x;
    __shared__ __align__(16) unsigned short sA[64 * P];    // V^T tile [v][l]
    __shared__ __align__(16) unsigned short sB[128 * P];   // phiK^T [i][l]
    const size_t base = ((size_t)b * L + (size_t)c * C) * D;

    // stage A: lanes vary l (transposed read; LDS b16 scatter 2-way = free)
    for (int k = 0; k < 8; ++k) {
        int fi = tid + 256 * k;
        int l = fi & 127, v4 = fi >> 7;   // v4: 0..15
        float4 vd = *(const float4*)(V + base + (size_t)l * D + vs * 64 + v4 * 4);
        sA[(v4 * 4 + 0) * P + l] = f2bf(vd.x);
        sA[(v4 * 4 + 1) * P + l] = f2bf(vd.y);
        sA[(v4 * 4 + 2) * P + l] = f2bf(vd.z);
        sA[(v4 * 4 + 3) * P + l] = f2bf(vd.w);
    }
    // stage B: phiK^T [i][l]
    for (int k = 0; k < 16; ++k) {
        int fi = tid + 256 * k;
        int l = fi & 127, i4 = fi >> 7;   // i4: 0..31
        float4 kd = *(const float4*)(K + base + (size_t)l * D + i4 * 4);
        sB[(i4 * 4 + 0) * P + l] = f2bf(phi(kd.x));
        sB[(i4 * 4 + 1) * P + l] = f2bf(phi(kd.y));
        sB[(i4 * 4 + 2) * P + l] = f2bf(phi(kd.z));
        sB[(i4 * 4 + 3) * P + l] = f2bf(phi(kd.w));
    }
    __syncthreads();

    // ksum[i] = sum_l phiK[l][i]  (vs==0 only; rotated dword reads)
    if (vs == 0 && tid < 128) {
        const unsigned* row = (const unsigned*)(sB + tid * P);
        float s = 0.0f;
        for (int j = 0; j < 64; ++j) {
            unsigned d = row[(tid + j) & 63];
            s += bf2f((unsigned short)(d & 0xffff)) + bf2f((unsigned short)(d >> 16));
        }
        Ksum[((size_t)(b * NC + c)) * D + tid] = s;
    }

    // GEMM: C 64x128, wave w rows w*16..+15, all 128 cols (8 frags)
    const int w = tid >> 6, lane = tid & 63;
    const int r = lane & 15, q = lane >> 4;
    f4 acc[8];
#pragma unroll
    for (int f = 0; f < 8; ++f) acc[f] = {0.f, 0.f, 0.f, 0.f};
#pragma unroll
    for (int ks = 0; ks < 4; ++ks) {
        sh8 a = *(const sh8*)(sA + (w * 16 + r) * P + ks * 32 + q * 8);
#pragma unroll
        for (int f = 0; f < 8; ++f) {
            sh8 bb = *(const sh8*)(sB + (f * 16 + r) * P + ks * 32 + q * 8);
            acc[f] = __builtin_amdgcn_mfma_f32_16x16x32_bf16(a, bb, acc[f], 0, 0, 0);
        }
    }
    // store chunk sums bf16: SB[b][c][v][i]
    unsigned short* out = SB + ((size_t)(b * NC + c)) * D * D;
#pragma unroll
    for (int f = 0; f < 8; ++f) {
        int i = f * 16 + r;
#pragma unroll
        for (int e = 0; e < 4; ++e) {
            int v = vs * 64 + w * 16 + q * 4 + e;
            out[(size_t)v * D + i] = f2bf(acc[f][e]);
        }
    }
}

// ---------------------------------------------------------------------------
// k_scan: exclusive prefix over chunk axis. SB bf16 in place (fp32 running
// sum), Ksum fp32 in place.
// ---------------------------------------------------------------------------
__global__ __launch_bounds__(256) void k_scan(unsigned short* __restrict__ SB,
                                              float* __restrict__ Ksum) {
    const int SD = D * D;
    int idx = blockIdx.x * 256 + threadIdx.x;
    if (idx < Bc * SD) {
        int b = idx / SD, e = idx % SD;
        float run = 0.0f;
        for (int c = 0; c < NC; ++c) {
            size_t off = ((size_t)(b * NC + c)) * SD + e;
            float t = bf2f(SB[off]);
            SB[off]  = f2bf(run);
            run += t;
        }
    } else if (idx < Bc * SD + Bc * D) {
        int rr = idx - Bc * SD;
        int b = rr >> 7, i = rr & 127;
        float run = 0.0f;
        for (int c = 0; c < NC; ++c) {
            size_t off = ((size_t)(b * NC + c)) * D + i;
            float t = Ksum[off];
            Ksum[off] = run;
            run += t;
        }
    }
}

// ---------------------------------------------------------------------------
// k_out: grid (NC, B, 4), rows split 4x32. 256 threads = 4 waves, each wave
// 16 rows x 64 cols (4 frags). One reused 128xP B-buffer; LDS ~53 KB.
// ---------------------------------------------------------------------------
__global__ __launch_bounds__(256) void k_out(
    const float* __restrict__ Q, const float* __restrict__ K,
    const float* __restrict__ V, const unsigned short* __restrict__ SB,
    const float* __restrict__ Ksum, float* __restrict__ Out) {
    const int c = blockIdx.x, b = blockIdx.y, rs = blockIdx.z;
    const int tid = threadIdx.x;
    __shared__ __align__(16) unsigned short sQ[32 * P];    // phiQ rows [lr][i]
    __shared__ __align__(16) unsigned short sB[128 * P];   // phiK / V^T / S^T
    __shared__ __align__(16) unsigned short sAm[32 * P];   // masked A bf16
    __shared__ float sKp[128];
    __shared__ float sZ[32];
    const size_t base  = ((size_t)b * L + (size_t)c * C) * D;
    const size_t qbase = base + (size_t)rs * 32 * D;

    // stage phiQ (row-major, packed 8B LDS writes)
    for (int k = 0; k < 4; ++k) {
        int fi = tid + 256 * k;
        int row = fi >> 5, c4 = fi & 31;
        float4 qd = *(const float4*)(Q + qbase + (size_t)row * D + c4 * 4);
        uint2 pk;
        pk.x = (unsigned)f2bf(phi(qd.x)) | ((unsigned)f2bf(phi(qd.y)) << 16);
        pk.y = (unsigned)f2bf(phi(qd.z)) | ((unsigned)f2bf(phi(qd.w)) << 16);
        *(uint2*)(sQ + row * P + c4 * 4) = pk;
    }
    // stage B = phiK rows (row-major [j][i])
    for (int k = 0; k < 16; ++k) {
        int fi = tid + 256 * k;
        int row = fi >> 5, c4 = fi & 31;
        float4 kd = *(const float4*)(K + base + (size_t)row * D + c4 * 4);
        uint2 pk;
        pk.x = (unsigned)f2bf(phi(kd.x)) | ((unsigned)f2bf(phi(kd.y)) << 16);
        pk.y = (unsigned)f2bf(phi(kd.z)) | ((unsigned)f2bf(phi(kd.w)) << 16);
        *(uint2*)(sB + row * P + c4 * 4) = pk;
    }
    if (tid < 128) sKp[tid] = Ksum[((size_t)(b * NC + c)) * D + tid];
    __syncthreads();

    const int w = tid >> 6, lane = tid & 63;
    const int r = lane & 15, q = lane >> 4;
    const int rbase = (w & 1) * 16;      // row sub-block (of 32)
    const int cbase = (w >> 1) * 64;     // col sub-block (of 128)

    // ---- GEMM2: A = phiQ phiK^T ----
    f4 a2[4];
#pragma unroll
    for (int f = 0; f < 4; ++f) a2[f] = {0.f, 0.f, 0.f, 0.f};
#pragma unroll
    for (int ks = 0; ks < 4; ++ks) {
        sh8 a = *(const sh8*)(sQ + (rbase + r) * P + ks * 32 + q * 8);
#pragma unroll
        for (int f = 0; f < 4; ++f) {
            sh8 bb = *(const sh8*)(sB + (cbase + f * 16 + r) * P + ks * 32 + q * 8);
            a2[f] = __builtin_amdgcn_mfma_f32_16x16x32_bf16(a, bb, a2[f], 0, 0, 0);
        }
    }
    // causal mask (within-chunk row = rs*32+lr), bf16, to LDS Am
#pragma unroll
    for (int f = 0; f < 4; ++f) {
        int j = cbase + f * 16 + r;
#pragma unroll
        for (int e = 0; e < 4; ++e) {
            int lr = rbase + q * 4 + e;
            float vv = (j <= rs * 32 + lr) ? a2[f][e] : 0.0f;
            sAm[lr * P + j] = f2bf(vv);
        }
    }
    __syncthreads();

    // restage B = V^T [v][j] (transposed read; 2-way LDS scatter = free)
    for (int k = 0; k < 16; ++k) {
        int fi = tid + 256 * k;
        int j = fi & 127, v4 = fi >> 7;   // v4: 0..31
        float4 vd = *(const float4*)(V + base + (size_t)j * D + v4 * 4);
        sB[(v4 * 4 + 0) * P + j] = f2bf(vd.x);
        sB[(v4 * 4 + 1) * P + j] = f2bf(vd.y);
        sB[(v4 * 4 + 2) * P + j] = f2bf(vd.z);
        sB[(v4 * 4 + 3) * P + j] = f2bf(vd.w);
    }
    // z per row: intra rowsum(Am) + inter phiQ.kprev (rotated dword reads)
    if (tid < 32) {
        const unsigned* am = (const unsigned*)(sAm + tid * P);
        const unsigned* qq = (const unsigned*)(sQ + tid * P);
        float zi = 0.0f, zn = 0.0f;
        for (int j = 0; j < 64; ++j) {
            int jj = (tid + j) & 63;
            unsigned da = am[jj];
            zi += bf2f((unsigned short)(da & 0xffff)) + bf2f((unsigned short)(da >> 16));
            unsigned dq = qq[jj];
            zn += bf2f((unsigned short)(dq & 0xffff)) * sKp[2 * jj]
                + bf2f((unsigned short)(dq >> 16))    * sKp[2 * jj + 1];
        }
        sZ[tid] = zi + zn + EPS;
    }
    __syncthreads();

    // ---- GEMM3: acc = Am @ V ----
    f4 acc[4];
#pragma unroll
    for (int f = 0; f < 4; ++f) acc[f] = {0.f, 0.f, 0.f, 0.f};
#pragma unroll
    for (int ks = 0; ks < 4; ++ks) {
        sh8 a = *(const sh8*)(sAm + (rbase + r) * P + ks * 32 + q * 8);
#pragma unroll
        for (int f = 0; f < 4; ++f) {
            sh8 bb = *(const sh8*)(sB + (cbase + f * 16 + r) * P + ks * 32 + q * 8);
            acc[f] = __builtin_amdgcn_mfma_f32_16x16x32_bf16(a, bb, acc[f], 0, 0, 0);
        }
    }
    __syncthreads();

    // restage B = S_prev^T [v][i] (row-major bf16 copy: 16 uint4 per 128-row)
    const uint4* sbg = (const uint4*)(SB + ((size_t)(b * NC + c)) * D * D);
    for (int k = 0; k < 8; ++k) {
        int fi = tid + 256 * k;           // 0..2047 uint4s
        int v = fi >> 4, ch = fi & 15;    // FIXED (was >>3 / &7: OOB scribble)
        uint4 dd = sbg[fi];
        *(uint4*)(sB + v * P + ch * 8) = dd;
    }
    __syncthreads();

    // ---- GEMM4: acc += phiQ @ S_prev ----
#pragma unroll
    for (int ks = 0; ks < 4; ++ks) {
        sh8 a = *(const sh8*)(sQ + (rbase + r) * P + ks * 32 + q * 8);
#pragma unroll
        for (int f = 0; f < 4; ++f) {
            sh8 bb = *(const sh8*)(sB + (cbase + f * 16 + r) * P + ks * 32 + q * 8);
            acc[f] = __builtin_amdgcn_mfma_f32_16x16x32_bf16(a, bb, acc[f], 0, 0, 0);
        }
    }

    // normalize + store
#pragma unroll
    for (int f = 0; f < 4; ++f) {
        int v = cbase + f * 16 + r;
#pragma unroll
        for (int e = 0; e < 4; ++e) {
            int lr = rbase + q * 4 + e;
            Out[base + (size_t)(rs * 32 + lr) * D + v] = acc[f][e] / sZ[lr];
        }
    }
}

extern "C" void kernel_launch(void* const* d_in, const int* in_sizes, int n_in,
                              void* d_out, int out_size, void* d_ws, size_t ws_size,
                              hipStream_t stream) {
    const float* Q = (const float*)d_in[0];
    const float* K = (const float*)d_in[1];
    const float* V = (const float*)d_in[2];
    float* Out = (float*)d_out;
    unsigned short* SB = (unsigned short*)d_ws;                 // 2 MB bf16
    float* Ksum = (float*)((char*)d_ws + (size_t)Bc * NC * D * D * 2);  // 32 KB

    k1<<<dim3(NC, Bc, 2), 256, 0, stream>>>(K, V, SB, Ksum);
    int total = Bc * D * D + Bc * D;
    k_scan<<<dim3((total + 255) / 256), 256, 0, stream>>>(SB, Ksum);
    k_out<<<dim3(NC, Bc, 4), 256, 0, stream>>>(Q, K, V, SB, Ksum, Out);
}

// Round 4
// 80.669 us; speedup vs baseline: 1.8624x; 1.0430x over previous
//
#include <hip/hip_runtime.h>

// Causal linear attention (ELU+1), chunked, bf16-MFMA. R4: 512-thread blocks
// (2 waves/SIMD), z & ksum folded into MFMA via ones/kprev extra B/A rows,
// 4 syncs, all staging up-front. ~48us of dur_us is harness ws-poison fill
// (256MB @ ~44us) + input restore — not controllable from kernel source.

#define EPS 1e-6f

constexpr int Bc = 2;
constexpr int L  = 4096;
constexpr int D  = 128;
constexpr int C  = 128;
constexpr int NC = L / C;   // 32
constexpr int P  = 136;     // LDS row pitch (bf16), rows 16B-aligned

typedef short sh8 __attribute__((ext_vector_type(8)));
typedef float f4  __attribute__((ext_vector_type(4)));

__device__ __forceinline__ float phi(float x) {
    return x > 0.0f ? x + 1.0f : __expf(x);
}
__device__ __forceinline__ unsigned short f2bf(float f) {
    unsigned u = __float_as_uint(f);
    return (unsigned short)((u + 0x7FFFu + ((u >> 16) & 1u)) >> 16);  // RNE
}
__device__ __forceinline__ float bf2f(unsigned short h) {
    return __uint_as_float(((unsigned)h) << 16);
}

// ---------------------------------------------------------------------------
// k1: ST[v][i] = sum_l V[l][v] phiK[l][i] (bf16 out) + ksum via ones-row.
// grid (NC, B, 2) = 128 blocks x 512 threads (8 waves).
// sA rows 64..79: row 64 = ones (ksum A-frag), 65..79 zero.
// ---------------------------------------------------------------------------
__global__ __launch_bounds__(512) void k1(
    const float* __restrict__ K, const float* __restrict__ V,
    unsigned short* __restrict__ SB, float* __restrict__ Ksum) {
    const int c = blockIdx.x, b = blockIdx.y, vs = blockIdx.z;
    const int tid = threadIdx.x;
    __shared__ __align__(16) unsigned short sA[80 * P];    // V^T [v][l] + ones
    __shared__ __align__(16) unsigned short sKb[128 * P];  // phiK^T [i][l]
    const size_t base = ((size_t)b * L + (size_t)c * C) * D;

    // stage A: V^T (transposed global read; LDS b16 writes 2-way = free)
    for (int k = 0; k < 4; ++k) {
        int fi = tid + 512 * k;           // 0..2047
        int l = fi & 127, v4 = fi >> 7;   // v4 0..15
        float4 vd = *(const float4*)(V + base + (size_t)l * D + vs * 64 + v4 * 4);
        sA[(v4 * 4 + 0) * P + l] = f2bf(vd.x);
        sA[(v4 * 4 + 1) * P + l] = f2bf(vd.y);
        sA[(v4 * 4 + 2) * P + l] = f2bf(vd.z);
        sA[(v4 * 4 + 3) * P + l] = f2bf(vd.w);
    }
    // rows 64..79: ones row 64, zeros 65..79 (16 rows x 64 dwords)
    for (int k = 0; k < 2; ++k) {
        int fi = tid + 512 * k;           // 0..1023
        int row = fi >> 6, colp = fi & 63;
        *(unsigned*)(sA + (64 + row) * P + colp * 2) = (row == 0) ? 0x3F803F80u : 0u;
    }
    // stage B: phiK^T [i][l]
    for (int k = 0; k < 8; ++k) {
        int fi = tid + 512 * k;           // 0..4095
        int l = fi & 127, i4 = fi >> 7;   // i4 0..31
        float4 kd = *(const float4*)(K + base + (size_t)l * D + i4 * 4);
        sKb[(i4 * 4 + 0) * P + l] = f2bf(phi(kd.x));
        sKb[(i4 * 4 + 1) * P + l] = f2bf(phi(kd.y));
        sKb[(i4 * 4 + 2) * P + l] = f2bf(phi(kd.z));
        sKb[(i4 * 4 + 3) * P + l] = f2bf(phi(kd.w));
    }
    __syncthreads();

    const int w = tid >> 6, lane = tid & 63;
    const int r = lane & 15, q = lane >> 4;
    const int rbase = (w & 3) * 16;       // v rows within 64
    const int cbase = (w >> 2) * 64;      // i cols (2 groups of 64)
    const bool doZ = (vs == 0) && ((w & 3) == 0);

    f4 acc[4], kz[4];
#pragma unroll
    for (int f = 0; f < 4; ++f) { acc[f] = {0.f,0.f,0.f,0.f}; kz[f] = {0.f,0.f,0.f,0.f}; }
#pragma unroll
    for (int ks = 0; ks < 4; ++ks) {
        sh8 a  = *(const sh8*)(sA + (rbase + r) * P + ks * 32 + q * 8);
        sh8 az = *(const sh8*)(sA + (64 + r) * P + ks * 32 + q * 8);
#pragma unroll
        for (int f = 0; f < 4; ++f) {
            sh8 bb = *(const sh8*)(sKb + (cbase + f * 16 + r) * P + ks * 32 + q * 8);
            acc[f] = __builtin_amdgcn_mfma_f32_16x16x32_bf16(a, bb, acc[f], 0, 0, 0);
            if (doZ) kz[f] = __builtin_amdgcn_mfma_f32_16x16x32_bf16(az, bb, kz[f], 0, 0, 0);
        }
    }
    unsigned short* out = SB + ((size_t)(b * NC + c)) * D * D;
#pragma unroll
    for (int f = 0; f < 4; ++f) {
        int i = cbase + f * 16 + r;
#pragma unroll
        for (int e = 0; e < 4; ++e) {
            int v = vs * 64 + rbase + q * 4 + e;
            out[(size_t)v * D + i] = f2bf(acc[f][e]);
        }
    }
    if (doZ && q == 0) {   // kz row 64 lives in q==0, reg 0
#pragma unroll
        for (int f = 0; f < 4; ++f)
            Ksum[((size_t)(b * NC + c)) * D + cbase + f * 16 + r] = kz[f][0];
    }
}

// ---------------------------------------------------------------------------
// k_scan: exclusive prefix over chunk axis (bf16 SB, fp32 Ksum), in place.
// ---------------------------------------------------------------------------
__global__ __launch_bounds__(256) void k_scan(unsigned short* __restrict__ SB,
                                              float* __restrict__ Ksum) {
    const int SD = D * D;
    int idx = blockIdx.x * 256 + threadIdx.x;
    if (idx < Bc * SD) {
        int b = idx / SD, e = idx % SD;
        float run = 0.0f;
        for (int c = 0; c < NC; ++c) {
            size_t off = ((size_t)(b * NC + c)) * SD + e;
            float t = bf2f(SB[off]);
            SB[off]  = f2bf(run);
            run += t;
        }
    } else if (idx < Bc * SD + Bc * D) {
        int rr = idx - Bc * SD;
        int b = rr >> 7, i = rr & 127;
        float run = 0.0f;
        for (int c = 0; c < NC; ++c) {
            size_t off = ((size_t)(b * NC + c)) * D + i;
            float t = Ksum[off];
            Ksum[off] = run;
            run += t;
        }
    }
}

// ---------------------------------------------------------------------------
// k_out: grid (NC, B, 4) rows split 4x32, 512 threads (8 waves).
// Waves: rbase=(w&1)*16 (row half), cq=w>>1 col quarter (32 cols, 2 frags).
// z via B-row 128: sV row128=ones (GEMM3->rowsum(Am)), sSb row128=kprev
// (GEMM4->phiQ.kprev); waves cq==3 accumulate the z frag.  4 syncs.
// LDS ~93.6 KB -> 1 block/CU, 8 waves.
// ---------------------------------------------------------------------------
__global__ __launch_bounds__(512) void k_out(
    const float* __restrict__ Q, const float* __restrict__ K,
    const float* __restrict__ V, const unsigned short* __restrict__ SB,
    const float* __restrict__ Ksum, float* __restrict__ Out) {
    const int c = blockIdx.x, b = blockIdx.y, rs = blockIdx.z;
    const int tid = threadIdx.x;
    __shared__ __align__(16) unsigned short sQ[32 * P];
    __shared__ __align__(16) unsigned short sKb[144 * P];  // phiK, then S^T+kprev
    __shared__ __align__(16) unsigned short sV[144 * P];   // V^T + ones row
    __shared__ __align__(16) unsigned short sAm[32 * P];
    __shared__ float sZ[32];
    const size_t base  = ((size_t)b * L + (size_t)c * C) * D;
    const size_t qbase = base + (size_t)rs * 32 * D;

    // ---- stage everything (one sync) ----
    for (int k = 0; k < 2; ++k) {        // phiQ rows: 1024 float4
        int fi = tid + 512 * k;
        int row = fi >> 5, c4 = fi & 31;
        float4 qd = *(const float4*)(Q + qbase + (size_t)row * D + c4 * 4);
        uint2 pk;
        pk.x = (unsigned)f2bf(phi(qd.x)) | ((unsigned)f2bf(phi(qd.y)) << 16);
        pk.y = (unsigned)f2bf(phi(qd.z)) | ((unsigned)f2bf(phi(qd.w)) << 16);
        *(uint2*)(sQ + row * P + c4 * 4) = pk;
    }
    for (int k = 0; k < 8; ++k) {        // phiK rows [j][i]: 4096 float4
        int fi = tid + 512 * k;
        int row = fi >> 5, c4 = fi & 31;
        float4 kd = *(const float4*)(K + base + (size_t)row * D + c4 * 4);
        uint2 pk;
        pk.x = (unsigned)f2bf(phi(kd.x)) | ((unsigned)f2bf(phi(kd.y)) << 16);
        pk.y = (unsigned)f2bf(phi(kd.z)) | ((unsigned)f2bf(phi(kd.w)) << 16);
        *(uint2*)(sKb + row * P + c4 * 4) = pk;
    }
    for (int k = 0; k < 8; ++k) {        // V^T [v][j]: transposed reads
        int fi = tid + 512 * k;
        int j = fi & 127, v4 = fi >> 7;  // v4 0..31
        float4 vd = *(const float4*)(V + base + (size_t)j * D + v4 * 4);
        sV[(v4 * 4 + 0) * P + j] = f2bf(vd.x);
        sV[(v4 * 4 + 1) * P + j] = f2bf(vd.y);
        sV[(v4 * 4 + 2) * P + j] = f2bf(vd.z);
        sV[(v4 * 4 + 3) * P + j] = f2bf(vd.w);
    }
    for (int k = 0; k < 2; ++k) {        // sV rows 128..143: ones row 128
        int fi = tid + 512 * k;
        int row = fi >> 6, colp = fi & 63;
        *(unsigned*)(sV + (128 + row) * P + colp * 2) = (row == 0) ? 0x3F803F80u : 0u;
    }
    __syncthreads();                     // S1

    const int w = tid >> 6, lane = tid & 63;
    const int r = lane & 15, q = lane >> 4;
    const int rbase = (w & 1) * 16;
    const int cq = w >> 1, cbase = cq * 32;
    const bool doZ = (cq == 3);

    // ---- GEMM2: A = phiQ phiK^T ----
    f4 a2[2];
#pragma unroll
    for (int f = 0; f < 2; ++f) a2[f] = {0.f,0.f,0.f,0.f};
#pragma unroll
    for (int ks = 0; ks < 4; ++ks) {
        sh8 a = *(const sh8*)(sQ + (rbase + r) * P + ks * 32 + q * 8);
#pragma unroll
        for (int f = 0; f < 2; ++f) {
            sh8 bb = *(const sh8*)(sKb + (cbase + f * 16 + r) * P + ks * 32 + q * 8);
            a2[f] = __builtin_amdgcn_mfma_f32_16x16x32_bf16(a, bb, a2[f], 0, 0, 0);
        }
    }
#pragma unroll
    for (int f = 0; f < 2; ++f) {        // causal mask -> sAm (bf16)
        int j = cbase + f * 16 + r;
#pragma unroll
        for (int e = 0; e < 4; ++e) {
            int lr = rbase + q * 4 + e;
            sAm[lr * P + j] = f2bf((j <= rs * 32 + lr) ? a2[f][e] : 0.0f);
        }
    }
    __syncthreads();                     // S2 (sAm ready; sKb free)

    // ---- restage sKb = S_prev^T + kprev row + zeros (overlaps GEMM3) ----
    {
        const uint4* sbg = (const uint4*)(SB + ((size_t)(b * NC + c)) * D * D);
        for (int k = 0; k < 4; ++k) {
            int fi = tid + 512 * k;      // 0..2047 uint4
            int v = fi >> 4, ch = fi & 15;
            uint4 dd = sbg[fi];
            *(uint4*)(sKb + v * P + ch * 8) = dd;
        }
        if (tid < 32) {                  // row 128 = kprev (bf16)
            float4 kq = ((const float4*)(Ksum + ((size_t)(b * NC + c)) * D))[tid];
            uint2 pk;
            pk.x = (unsigned)f2bf(kq.x) | ((unsigned)f2bf(kq.y) << 16);
            pk.y = (unsigned)f2bf(kq.z) | ((unsigned)f2bf(kq.w) << 16);
            *(uint2*)(sKb + 128 * P + tid * 4) = pk;
        }
        for (int k = 0; k < 2; ++k) {    // rows 129..143 zero (960 dwords)
            int fi = tid + 512 * k;
            if (fi < 960) {
                int row = 129 + (fi >> 6), colp = fi & 63;
                *(unsigned*)(sKb + row * P + colp * 2) = 0u;
            }
        }
    }

    // ---- GEMM3: acc = Am @ V (+ z rowsum frag on cq==3) ----
    f4 acc[2], zacc = {0.f,0.f,0.f,0.f};
#pragma unroll
    for (int f = 0; f < 2; ++f) acc[f] = {0.f,0.f,0.f,0.f};
#pragma unroll
    for (int ks = 0; ks < 4; ++ks) {
        sh8 a = *(const sh8*)(sAm + (rbase + r) * P + ks * 32 + q * 8);
#pragma unroll
        for (int f = 0; f < 2; ++f) {
            sh8 bb = *(const sh8*)(sV + (cbase + f * 16 + r) * P + ks * 32 + q * 8);
            acc[f] = __builtin_amdgcn_mfma_f32_16x16x32_bf16(a, bb, acc[f], 0, 0, 0);
        }
        if (doZ) {
            sh8 bz = *(const sh8*)(sV + (128 + r) * P + ks * 32 + q * 8);
            zacc = __builtin_amdgcn_mfma_f32_16x16x32_bf16(a, bz, zacc, 0, 0, 0);
        }
    }
    __syncthreads();                     // S3 (sKb = S^T ready)

    // ---- GEMM4: acc += phiQ @ S_prev (+ z kprev frag on cq==3) ----
#pragma unroll
    for (int ks = 0; ks < 4; ++ks) {
        sh8 a = *(const sh8*)(sQ + (rbase + r) * P + ks * 32 + q * 8);
#pragma unroll
        for (int f = 0; f < 2; ++f) {
            sh8 bb = *(const sh8*)(sKb + (cbase + f * 16 + r) * P + ks * 32 + q * 8);
            acc[f] = __builtin_amdgcn_mfma_f32_16x16x32_bf16(a, bb, acc[f], 0, 0, 0);
        }
        if (doZ) {
            sh8 bz = *(const sh8*)(sKb + (128 + r) * P + ks * 32 + q * 8);
            zacc = __builtin_amdgcn_mfma_f32_16x16x32_bf16(a, bz, zacc, 0, 0, 0);
        }
    }
    if (doZ && r == 0) {                 // z col 0 of frag -> lanes r==0
#pragma unroll
        for (int e = 0; e < 4; ++e) sZ[rbase + q * 4 + e] = zacc[e] + EPS;
    }
    __syncthreads();                     // S4 (sZ ready)

    // ---- normalize + store ----
#pragma unroll
    for (int f = 0; f < 2; ++f) {
        int v = cbase + f * 16 + r;
#pragma unroll
        for (int e = 0; e < 4; ++e) {
            int lr = rbase + q * 4 + e;
            Out[base + (size_t)(rs * 32 + lr) * D + v] = acc[f][e] / sZ[lr];
        }
    }
}

extern "C" void kernel_launch(void* const* d_in, const int* in_sizes, int n_in,
                              void* d_out, int out_size, void* d_ws, size_t ws_size,
                              hipStream_t stream) {
    const float* Q = (const float*)d_in[0];
    const float* K = (const float*)d_in[1];
    const float* V = (const float*)d_in[2];
    float* Out = (float*)d_out;
    unsigned short* SBw = (unsigned short*)d_ws;                 // 2 MB bf16
    float* Ksum = (float*)((char*)d_ws + (size_t)Bc * NC * D * D * 2);

    k1<<<dim3(NC, Bc, 2), 512, 0, stream>>>(K, V, SBw, Ksum);
    int total = Bc * D * D + Bc * D;
    k_scan<<<dim3((total + 255) / 256), 256, 0, stream>>>(SBw, Ksum);
    k_out<<<dim3(NC, Bc, 4), 512, 0, stream>>>(Q, K, V, SBw, Ksum, Out);
}